// Round 3
// baseline (2689.752 us; speedup 1.0000x reference)
//
#include <hip/hip_runtime.h>
#include <math.h>
#include <stdint.h>

// NeuralMJP forward, MI355X/gfx950.
//  * sample == one-hot(argmax(logits)) in fwd -> decoder = 32x32 table.
//  * argmax(softmax(z)) == argmax(z) -> y never materialized.
//  * fp32 only (no fp32 MFMA; bf16 flips Gumbel argmaxes -> catastrophic).
//  * Weight delivery history:
//      R1 SMEM/s_load: out-of-order returns -> lgkmcnt(0) drain per j-iter,
//         K$ misses (34.8KB slab > 16KB K$) -> VALUBusy 38%, 670us.
//      R2 LDS broadcast: DS pipe is per-CU, ~12cyc/ds_read_b128 even for
//         broadcast; 17 ds/iter x 16 waves vs 4 VALU pipes -> DS-bound, 818us.
//      R3 (this): vector path. global_load is IN-ORDER (fine-grained vmcnt),
//         TA ~1 req/cyc/CU >> demand 0.47 req/cyc; rows L1-resident (32KB).
//         Uniformity defeated via offset loaded from memory (always 0) so
//         addresses stay in VGPRs -> global_load_dwordx4, not s_load.

constexpr int kB = 524288;  // batch
constexpr int kD = 32;      // input dim
constexpr int kH = 128;     // hidden
constexpr int kS = 32;      // states

// d_ws layout (bytes):
//   pw    @ 0      : 3*128*64 f32 = 98304   rows: [w1col(32) | w2row(32)]
//   pb1   @ 98304  : 3*128   f32 = 1536
//   table @ 99840  : 32*32   f32 = 4096
//   zoff  @ 103936 : 64      i32 = 256      (zeros; defeats uniformity analysis)

// -------- prep: pack weights + build decoder table ------------------------
__global__ __launch_bounds__(1024) void prep_kernel(
    const float* __restrict__ q_w1,  const float* __restrict__ q_b1,
    const float* __restrict__ q_w2,
    const float* __restrict__ gi_w1, const float* __restrict__ gi_b1,
    const float* __restrict__ gi_w2,
    const float* __restrict__ go_w1, const float* __restrict__ go_b1,
    const float* __restrict__ go_w2,
    const float* __restrict__ dec_w1, const float* __restrict__ dec_b1,
    const float* __restrict__ dec_w2, const float* __restrict__ dec_b2,
    float* __restrict__ pw, float* __restrict__ pb1,
    float* __restrict__ table, int* __restrict__ zoff)
{
    const int t = threadIdx.x;
    // decoder table: row k = relu(dec_w1[k,:] + dec_b1) @ dec_w2 + dec_b2
    {
        const int k = t >> 5, d = t & 31;
        float acc = 0.0f;
        #pragma unroll 4
        for (int j = 0; j < kH; ++j) {
            float a = dec_w1[k * kH + j] + dec_b1[j];
            a = fmaxf(a, 0.0f);
            acc = fmaf(a, dec_w2[j * kS + d], acc);
        }
        table[k * kS + d] = acc + dec_b2[d];
    }
    // weight packing: 3*128 rows of 64 floats + compact b1 slab
    if (t < 3 * kH) {
        const int p = t >> 7;
        const int j = t & (kH - 1);
        const float* w1 = (p == 0) ? q_w1 : (p == 1) ? gi_w1 : go_w1;
        const float* w2 = (p == 0) ? q_w2 : (p == 1) ? gi_w2 : go_w2;
        const float* b1 = (p == 0) ? q_b1 : (p == 1) ? gi_b1 : go_b1;
        float* row = pw + (size_t)(p * kH + j) * 64;
        for (int i = 0; i < kD; ++i) row[i] = w1[i * kH + j];
        for (int s = 0; s < kS; ++s) row[32 + s] = w2[j * kS + s];
        pb1[t] = b1[j];
    }
    if (t < 64) zoff[t] = 0;   // d_ws is re-poisoned each launch; re-zero every call
}

// -------- main ------------------------------------------------------------
__device__ __forceinline__ void mlp_pass(const float* __restrict__ hv,
                                         const float* __restrict__ wbase, // VGPR addr
                                         const float* __restrict__ b1v,   // VGPR addr
                                         const float* __restrict__ b2,    // uniform
                                         float* __restrict__ lg)
{
    #pragma unroll
    for (int s = 0; s < kS; ++s) lg[s] = 0.0f;
    #pragma unroll 1
    for (int j = 0; j < kH; ++j) {   // rolled: predictable regs, in-order vmcnt pipelines
        const float4* __restrict__ wr4 =
            reinterpret_cast<const float4*>(wbase + j * 64);
        const float bias = b1v[j];          // oldest vmcnt -> ready first
        // phase 1: w1 column (32 floats)
        float wf[kD];
        #pragma unroll
        for (int k = 0; k < 8; ++k) {
            float4 t = wr4[k];
            wf[4 * k + 0] = t.x; wf[4 * k + 1] = t.y;
            wf[4 * k + 2] = t.z; wf[4 * k + 3] = t.w;
        }
        float a0 = 0.f, a1 = 0.f, a2 = 0.f, a3 = 0.f;
        #pragma unroll
        for (int i = 0; i < 8; ++i) {   // 4 chains: break fma latency serialization
            a0 = fmaf(hv[i],      wf[i],      a0);
            a1 = fmaf(hv[i + 8],  wf[i + 8],  a1);
            a2 = fmaf(hv[i + 16], wf[i + 16], a2);
            a3 = fmaf(hv[i + 24], wf[i + 24], a3);
        }
        float a = ((a0 + a1) + (a2 + a3)) + bias;  // dot, then bias (matches np)
        a = fmaxf(a, 0.0f);
        // phase 2: w2 row (32 floats)
        float vf[kS];
        #pragma unroll
        for (int k = 0; k < 8; ++k) {
            float4 t = wr4[8 + k];
            vf[4 * k + 0] = t.x; vf[4 * k + 1] = t.y;
            vf[4 * k + 2] = t.z; vf[4 * k + 3] = t.w;
        }
        #pragma unroll
        for (int s = 0; s < kS; ++s) lg[s] = fmaf(a, vf[s], lg[s]);
    }
    #pragma unroll
    for (int s = 0; s < kS; ++s) lg[s] += b2[s];
}

__device__ __forceinline__ float tree_sum32(const float* __restrict__ v)
{
    float b0 = 0.f, b1 = 0.f, b2 = 0.f, b3 = 0.f;
    #pragma unroll
    for (int i = 0; i < 8; ++i) {
        b0 += v[i]; b1 += v[i + 8]; b2 += v[i + 16]; b3 += v[i + 24];
    }
    return (b0 + b1) + (b2 + b3);   // pairwise-ish, like np.sum
}

__device__ __forceinline__ void softmax32(const float* __restrict__ lg,
                                          float* __restrict__ p)
{
    float m = lg[0];
    #pragma unroll
    for (int s = 1; s < kS; ++s) m = fmaxf(m, lg[s]);
    float e[kS];
    #pragma unroll
    for (int s = 0; s < kS; ++s) e[s] = expf(lg[s] - m);
    const float Z = tree_sum32(e);
    #pragma unroll
    for (int s = 0; s < kS; ++s) p[s] = e[s] / Z;  // precise div, like np
}

__global__ __launch_bounds__(256, 4) void main_kernel(
    const float* __restrict__ h, const float* __restrict__ u,
    const float* __restrict__ qb2, const float* __restrict__ gib2,
    const float* __restrict__ gob2,
    const float* __restrict__ pw, const float* __restrict__ pb1,
    const float* __restrict__ table, const int* __restrict__ zoff,
    float* __restrict__ out)
{
    const int tid = threadIdx.x;
    const int b = blockIdx.x * 256 + tid;

    // off == 0 always, but loaded from memory -> compiler can't prove uniform
    // -> weight addresses stay in VGPRs -> global_load (in-order vmcnt path).
    const int off = zoff[tid & 63];
    const float* __restrict__ pwv  = pw  + off;
    const float* __restrict__ pb1v = pb1 + off;

    float hv[kD];
    {
        const float4* h4 = reinterpret_cast<const float4*>(h + (size_t)b * kD);
        #pragma unroll
        for (int i = 0; i < 8; ++i) {
            float4 t = h4[i];
            hv[4 * i + 0] = t.x; hv[4 * i + 1] = t.y;
            hv[4 * i + 2] = t.z; hv[4 * i + 3] = t.w;
        }
    }

    float lg[kS], q[kS], gi[kS];

    mlp_pass(hv, pwv,               pb1v,           qb2,  lg);
    softmax32(lg, q);
    mlp_pass(hv, pwv + 1 * kH * 64, pb1v + 1 * kH,  gib2, lg);
    softmax32(lg, gi);
    mlp_pass(hv, pwv + 2 * kH * 64, pb1v + 2 * kH,  gob2, lg);

    // g_out softmax fused with gumbel argmax (y never materialized)
    float m3 = lg[0];
    #pragma unroll
    for (int s = 1; s < kS; ++s) m3 = fmaxf(m3, lg[s]);
    float e3[kS];
    #pragma unroll
    for (int s = 0; s < kS; ++s) e3[s] = expf(lg[s] - m3);
    const float Z3 = tree_sum32(e3);
    const float qs = tree_sum32(q);   // == sum(q), computed like the reference

    float uv[kS];
    {
        const float4* u4 = reinterpret_cast<const float4*>(u + (size_t)b * kS);
        #pragma unroll
        for (int i = 0; i < 8; ++i) {
            float4 t = u4[i];
            uv[4 * i + 0] = t.x; uv[4 * i + 1] = t.y;
            uv[4 * i + 2] = t.z; uv[4 * i + 3] = t.w;
        }
    }

    float best = -__builtin_inff();
    int bi = 0;
    {
        #pragma clang fp contract(off)   // match np's per-op rounding here
        #pragma unroll
        for (int s = 0; s < kS; ++s) {
            const float gos = e3[s] / Z3;
            const float t1 = gi[s] * (qs - q[s]);
            const float t2 = gos * q[s];
            const float qn = q[s] + (t1 + t2);
            const float gn = -logf(-logf(uv[s] + 1e-20f) + 1e-20f);
            const float v  = logf(qn + 1e-12f) + gn;
            if (v > best) { best = v; bi = s; }   // strict >: first-index ties, like np.argmax
        }
    }

    // out[b,:] = table[bi,:]
    const float4* trow = reinterpret_cast<const float4*>(table + (size_t)bi * kS);
    float4* orow = reinterpret_cast<float4*>(out + (size_t)b * kD);
    #pragma unroll
    for (int i = 0; i < 8; ++i) orow[i] = trow[i];
}

extern "C" void kernel_launch(void* const* d_in, const int* in_sizes, int n_in,
                              void* d_out, int out_size, void* d_ws, size_t ws_size,
                              hipStream_t stream)
{
    const float* h      = (const float*)d_in[0];
    const float* u      = (const float*)d_in[1];
    const float* q_w1   = (const float*)d_in[2];
    const float* q_b1   = (const float*)d_in[3];
    const float* q_w2   = (const float*)d_in[4];
    const float* q_b2   = (const float*)d_in[5];
    const float* gi_w1  = (const float*)d_in[6];
    const float* gi_b1  = (const float*)d_in[7];
    const float* gi_w2  = (const float*)d_in[8];
    const float* gi_b2  = (const float*)d_in[9];
    const float* go_w1  = (const float*)d_in[10];
    const float* go_b1  = (const float*)d_in[11];
    const float* go_w2  = (const float*)d_in[12];
    const float* go_b2  = (const float*)d_in[13];
    const float* dec_w1 = (const float*)d_in[14];
    const float* dec_b1 = (const float*)d_in[15];
    const float* dec_w2 = (const float*)d_in[16];
    const float* dec_b2 = (const float*)d_in[17];

    float* pw    = (float*)d_ws;                       // 98304 B
    float* pb1   = (float*)((char*)d_ws + 98304);      //  1536 B
    float* table = (float*)((char*)d_ws + 99840);      //  4096 B
    int*   zoff  = (int*)  ((char*)d_ws + 103936);     //   256 B
    float* out   = (float*)d_out;

    prep_kernel<<<1, 1024, 0, stream>>>(q_w1, q_b1, q_w2, gi_w1, gi_b1, gi_w2,
                                        go_w1, go_b1, go_w2,
                                        dec_w1, dec_b1, dec_w2, dec_b2,
                                        pw, pb1, table, zoff);
    main_kernel<<<kB / 256, 256, 0, stream>>>(h, u, q_b2, gi_b2, go_b2,
                                              pw, pb1, table, zoff, out);
}

// Round 4
// 1598.071 us; speedup vs baseline: 1.6831x; 1.6831x over previous
//
#include <hip/hip_runtime.h>
#include <math.h>
#include <stdint.h>

// NeuralMJP forward, MI355X/gfx950.
//  * sample == one-hot(argmax(logits)) in fwd -> decoder = 32x32 table.
//  * argmax(softmax(z)) == argmax(z) -> y never materialized.
//  * fp32 only (no fp32 MFMA; bf16 flips Gumbel argmaxes -> catastrophic).
//  * Weight delivery history:
//      R1 SMEM/s_load: OOO returns -> lgkmcnt(0) full drain per j-iter,
//         un-pipelineable -> VALUBusy 38%, 670us.
//      R2 LDS broadcast: DS pipe ~12cyc/ds_read_b128 even broadcast;
//         17 ds/iter vs 4 VALU pipes -> DS-bound, 818us.
//      R3 L1 vector path, arrays + launch_bounds(256,4): compiler spilled
//         (VGPR=64, WRITE_SIZE 576MB of scratch) -> 2675us. Concept OK:
//         TA 102 cyc/elem < VALU 192 cyc/elem -> VALU-bound if spill-free.
//      R4 (this): same path, named float4 temps (no arrays), two phases
//         per j (peak live ~110 regs), launch_bounds(256,2) -> cap 256.

constexpr int kB = 524288;  // batch
constexpr int kD = 32;      // input dim
constexpr int kH = 128;     // hidden
constexpr int kS = 32;      // states

// d_ws layout (bytes):
//   pw    @ 0      : 3*128*64 f32 = 98304   rows: [w1col(32) | w2row(32)]
//   pb1   @ 98304  : 3*128   f32 = 1536
//   table @ 99840  : 32*32   f32 = 4096
//   zoff  @ 103936 : 64      i32 = 256      (zeros; defeats uniformity analysis)

// -------- prep: pack weights + build decoder table ------------------------
__global__ __launch_bounds__(1024) void prep_kernel(
    const float* __restrict__ q_w1,  const float* __restrict__ q_b1,
    const float* __restrict__ q_w2,
    const float* __restrict__ gi_w1, const float* __restrict__ gi_b1,
    const float* __restrict__ gi_w2,
    const float* __restrict__ go_w1, const float* __restrict__ go_b1,
    const float* __restrict__ go_w2,
    const float* __restrict__ dec_w1, const float* __restrict__ dec_b1,
    const float* __restrict__ dec_w2, const float* __restrict__ dec_b2,
    float* __restrict__ pw, float* __restrict__ pb1,
    float* __restrict__ table, int* __restrict__ zoff)
{
    const int t = threadIdx.x;
    // decoder table: row k = relu(dec_w1[k,:] + dec_b1) @ dec_w2 + dec_b2
    {
        const int k = t >> 5, d = t & 31;
        float acc = 0.0f;
        #pragma unroll 4
        for (int j = 0; j < kH; ++j) {
            float a = dec_w1[k * kH + j] + dec_b1[j];
            a = fmaxf(a, 0.0f);
            acc = fmaf(a, dec_w2[j * kS + d], acc);
        }
        table[k * kS + d] = acc + dec_b2[d];
    }
    // weight packing: 3*128 rows of 64 floats + compact b1 slab
    if (t < 3 * kH) {
        const int p = t >> 7;
        const int j = t & (kH - 1);
        const float* w1 = (p == 0) ? q_w1 : (p == 1) ? gi_w1 : go_w1;
        const float* w2 = (p == 0) ? q_w2 : (p == 1) ? gi_w2 : go_w2;
        const float* b1 = (p == 0) ? q_b1 : (p == 1) ? gi_b1 : go_b1;
        float* row = pw + (size_t)(p * kH + j) * 64;
        for (int i = 0; i < kD; ++i) row[i] = w1[i * kH + j];
        for (int s = 0; s < kS; ++s) row[32 + s] = w2[j * kS + s];
        pb1[t] = b1[j];
    }
    if (t < 64) zoff[t] = 0;   // d_ws re-poisoned each launch; re-zero every call
}

// -------- main ------------------------------------------------------------
// 8 sequential fmafs into acc: EXACT same per-chain order as R1/R2/R3.
#define CHAIN8(acc, h0, wa, wb)                       \
    acc = fmaf(hv[(h0) + 0], (wa).x, acc);            \
    acc = fmaf(hv[(h0) + 1], (wa).y, acc);            \
    acc = fmaf(hv[(h0) + 2], (wa).z, acc);            \
    acc = fmaf(hv[(h0) + 3], (wa).w, acc);            \
    acc = fmaf(hv[(h0) + 4], (wb).x, acc);            \
    acc = fmaf(hv[(h0) + 5], (wb).y, acc);            \
    acc = fmaf(hv[(h0) + 6], (wb).z, acc);            \
    acc = fmaf(hv[(h0) + 7], (wb).w, acc);

#define RANK1_4(s0, xv)                               \
    lg[(s0) + 0] = fmaf(a, (xv).x, lg[(s0) + 0]);     \
    lg[(s0) + 1] = fmaf(a, (xv).y, lg[(s0) + 1]);     \
    lg[(s0) + 2] = fmaf(a, (xv).z, lg[(s0) + 2]);     \
    lg[(s0) + 3] = fmaf(a, (xv).w, lg[(s0) + 3]);

__device__ __forceinline__ void mlp_pass(const float* __restrict__ hv,
                                         const float* __restrict__ wbase, // VGPR addr
                                         const float* __restrict__ b1v,   // VGPR addr
                                         const float* __restrict__ b2,    // uniform
                                         float* __restrict__ lg)
{
    #pragma unroll
    for (int s = 0; s < kS; ++s) lg[s] = 0.0f;
    #pragma unroll 1
    for (int j = 0; j < kH; ++j) {   // rolled; in-order vmcnt pipelines loads
        const float4* __restrict__ wr4 =
            reinterpret_cast<const float4*>(wbase + j * 64);
        const float bias = b1v[j];
        // phase 1: w1 column (32 floats) -> dot via 4 independent chains
        float4 w0 = wr4[0], w1 = wr4[1], w2 = wr4[2], w3 = wr4[3];
        float4 w4 = wr4[4], w5 = wr4[5], w6 = wr4[6], w7 = wr4[7];
        float a0 = 0.f, a1 = 0.f, a2 = 0.f, a3 = 0.f;
        CHAIN8(a0, 0,  w0, w1)
        CHAIN8(a1, 8,  w2, w3)
        CHAIN8(a2, 16, w4, w5)
        CHAIN8(a3, 24, w6, w7)
        float a = ((a0 + a1) + (a2 + a3)) + bias;  // dot, then bias (matches np)
        a = fmaxf(a, 0.0f);
        // phase 2: w2 row (32 floats) -> rank-1 update, s ascending
        float4 x0 = wr4[8],  x1 = wr4[9],  x2 = wr4[10], x3 = wr4[11];
        float4 x4 = wr4[12], x5 = wr4[13], x6 = wr4[14], x7 = wr4[15];
        RANK1_4(0,  x0) RANK1_4(4,  x1) RANK1_4(8,  x2) RANK1_4(12, x3)
        RANK1_4(16, x4) RANK1_4(20, x5) RANK1_4(24, x6) RANK1_4(28, x7)
    }
    #pragma unroll
    for (int s = 0; s < kS; ++s) lg[s] += b2[s];
}

__device__ __forceinline__ float tree_sum32(const float* __restrict__ v)
{
    float b0 = 0.f, b1 = 0.f, b2 = 0.f, b3 = 0.f;
    #pragma unroll
    for (int i = 0; i < 8; ++i) {
        b0 += v[i]; b1 += v[i + 8]; b2 += v[i + 16]; b3 += v[i + 24];
    }
    return (b0 + b1) + (b2 + b3);   // pairwise-ish, like np.sum
}

__device__ __forceinline__ void softmax32(const float* __restrict__ lg,
                                          float* __restrict__ p)
{
    float m = lg[0];
    #pragma unroll
    for (int s = 1; s < kS; ++s) m = fmaxf(m, lg[s]);
    float e[kS];
    #pragma unroll
    for (int s = 0; s < kS; ++s) e[s] = expf(lg[s] - m);
    const float Z = tree_sum32(e);
    #pragma unroll
    for (int s = 0; s < kS; ++s) p[s] = e[s] / Z;  // precise div, like np
}

__global__ __launch_bounds__(256, 2) void main_kernel(
    const float* __restrict__ h, const float* __restrict__ u,
    const float* __restrict__ qb2, const float* __restrict__ gib2,
    const float* __restrict__ gob2,
    const float* __restrict__ pw, const float* __restrict__ pb1,
    const float* __restrict__ table, const int* __restrict__ zoff,
    float* __restrict__ out)
{
    const int tid = threadIdx.x;
    const int b = blockIdx.x * 256 + tid;

    // off == 0 always, but loaded from memory -> compiler can't prove uniform
    // -> weight addresses stay in VGPRs -> global_load (in-order vmcnt path).
    const int off = zoff[tid & 63];
    const float* __restrict__ pwv  = pw  + off;
    const float* __restrict__ pb1v = pb1 + off;

    float hv[kD];
    {
        const float4* h4 = reinterpret_cast<const float4*>(h + (size_t)b * kD);
        #pragma unroll
        for (int i = 0; i < 8; ++i) {
            float4 t = h4[i];
            hv[4 * i + 0] = t.x; hv[4 * i + 1] = t.y;
            hv[4 * i + 2] = t.z; hv[4 * i + 3] = t.w;
        }
    }

    float lg[kS], q[kS], gi[kS];

    mlp_pass(hv, pwv,               pb1v,           qb2,  lg);
    softmax32(lg, q);
    mlp_pass(hv, pwv + 1 * kH * 64, pb1v + 1 * kH,  gib2, lg);
    softmax32(lg, gi);
    mlp_pass(hv, pwv + 2 * kH * 64, pb1v + 2 * kH,  gob2, lg);

    // g_out softmax fused with gumbel argmax (y never materialized)
    float m3 = lg[0];
    #pragma unroll
    for (int s = 1; s < kS; ++s) m3 = fmaxf(m3, lg[s]);
    float e3[kS];
    #pragma unroll
    for (int s = 0; s < kS; ++s) e3[s] = expf(lg[s] - m3);
    const float Z3 = tree_sum32(e3);
    const float qs = tree_sum32(q);   // == sum(q), computed like the reference

    float uv[kS];
    {
        const float4* u4 = reinterpret_cast<const float4*>(u + (size_t)b * kS);
        #pragma unroll
        for (int i = 0; i < 8; ++i) {
            float4 t = u4[i];
            uv[4 * i + 0] = t.x; uv[4 * i + 1] = t.y;
            uv[4 * i + 2] = t.z; uv[4 * i + 3] = t.w;
        }
    }

    float best = -__builtin_inff();
    int bi = 0;
    {
        #pragma clang fp contract(off)   // match np's per-op rounding here
        #pragma unroll
        for (int s = 0; s < kS; ++s) {
            const float gos = e3[s] / Z3;
            const float t1 = gi[s] * (qs - q[s]);
            const float t2 = gos * q[s];
            const float qn = q[s] + (t1 + t2);
            const float gn = -logf(-logf(uv[s] + 1e-20f) + 1e-20f);
            const float v  = logf(qn + 1e-12f) + gn;
            if (v > best) { best = v; bi = s; }   // strict >: first-index ties, like np.argmax
        }
    }

    // out[b,:] = table[bi,:]
    const float4* trow = reinterpret_cast<const float4*>(table + (size_t)bi * kS);
    float4* orow = reinterpret_cast<float4*>(out + (size_t)b * kD);
    #pragma unroll
    for (int i = 0; i < 8; ++i) orow[i] = trow[i];
}

extern "C" void kernel_launch(void* const* d_in, const int* in_sizes, int n_in,
                              void* d_out, int out_size, void* d_ws, size_t ws_size,
                              hipStream_t stream)
{
    const float* h      = (const float*)d_in[0];
    const float* u      = (const float*)d_in[1];
    const float* q_w1   = (const float*)d_in[2];
    const float* q_b1   = (const float*)d_in[3];
    const float* q_w2   = (const float*)d_in[4];
    const float* q_b2   = (const float*)d_in[5];
    const float* gi_w1  = (const float*)d_in[6];
    const float* gi_b1  = (const float*)d_in[7];
    const float* gi_w2  = (const float*)d_in[8];
    const float* gi_b2  = (const float*)d_in[9];
    const float* go_w1  = (const float*)d_in[10];
    const float* go_b1  = (const float*)d_in[11];
    const float* go_w2  = (const float*)d_in[12];
    const float* go_b2  = (const float*)d_in[13];
    const float* dec_w1 = (const float*)d_in[14];
    const float* dec_b1 = (const float*)d_in[15];
    const float* dec_w2 = (const float*)d_in[16];
    const float* dec_b2 = (const float*)d_in[17];

    float* pw    = (float*)d_ws;                       // 98304 B
    float* pb1   = (float*)((char*)d_ws + 98304);      //  1536 B
    float* table = (float*)((char*)d_ws + 99840);      //  4096 B
    int*   zoff  = (int*)  ((char*)d_ws + 103936);     //   256 B
    float* out   = (float*)d_out;

    prep_kernel<<<1, 1024, 0, stream>>>(q_w1, q_b1, q_w2, gi_w1, gi_b1, gi_w2,
                                        go_w1, go_b1, go_w2,
                                        dec_w1, dec_b1, dec_w2, dec_b2,
                                        pw, pb1, table, zoff);
    main_kernel<<<kB / 256, 256, 0, stream>>>(h, u, q_b2, gi_b2, go_b2,
                                              pw, pb1, table, zoff, out);
}

// Round 5
// 655.634 us; speedup vs baseline: 4.1025x; 2.4374x over previous
//
#include <hip/hip_runtime.h>
#include <math.h>
#include <stdint.h>

// NeuralMJP forward, MI355X/gfx950.
//  * sample == one-hot(argmax(logits)) in fwd -> decoder = 32x32 table.
//  * argmax(softmax(z)) == argmax(z) -> y never materialized.
//  * fp32 only (no fp32 MFMA; bf16 flips Gumbel argmaxes -> catastrophic).
//  * Weight-delivery ladder (wave-uniform data replicates on EVERY pipe's
//    return path -> cost is per-instruction, not per-unique-byte):
//      R1 SMEM: OOO returns, lgkmcnt(0) drains + K$ thrash -> 670us.
//      R2 LDS 16x uniform b128/j: DS pipe ~9.4cyc each -> DS-bound, 818us.
//      R4 VMEM: L1 return 1KiB/wave-load, ~17.6cyc -> 1530us.
//      R5 (this): 4-way lane-quad split -> only 4 ds_read_b128/j (16
//        disjoint banks each, conflict-free multi-broadcast); quad-
//        broadcast fused into the FMA via v_fmac_f32_dpp quad_perm:[g,g,g,g]
//        (zero extra instructions); b1 via lane-resident VGPRs + v_readlane.
//        DS 451 vs VALU 432 cyc per j-round -> co-saturated.

constexpr int kB = 524288;  // batch
constexpr int kD = 32;      // input dim
constexpr int kH = 128;     // hidden
constexpr int kS = 32;      // states

// d_ws layout (bytes):
//   pw    @ 0     : 3*128*64 f32 = 98304   rows: [w1col(32) | w2row(32)]
//   pb1   @ 98304 : 3*128   f32 = 1536
//   table @ 99840 : 32*32   f32 = 4096

// -------- prep: pack weights + build decoder table ------------------------
__global__ __launch_bounds__(1024) void prep_kernel(
    const float* __restrict__ q_w1,  const float* __restrict__ q_b1,
    const float* __restrict__ q_w2,
    const float* __restrict__ gi_w1, const float* __restrict__ gi_b1,
    const float* __restrict__ gi_w2,
    const float* __restrict__ go_w1, const float* __restrict__ go_b1,
    const float* __restrict__ go_w2,
    const float* __restrict__ dec_w1, const float* __restrict__ dec_b1,
    const float* __restrict__ dec_w2, const float* __restrict__ dec_b2,
    float* __restrict__ pw, float* __restrict__ pb1, float* __restrict__ table)
{
    const int t = threadIdx.x;
    // decoder table: row k = relu(dec_w1[k,:] + dec_b1) @ dec_w2 + dec_b2
    {
        const int k = t >> 5, d = t & 31;
        float acc = 0.0f;
        #pragma unroll 4
        for (int j = 0; j < kH; ++j) {
            float a = dec_w1[k * kH + j] + dec_b1[j];
            a = fmaxf(a, 0.0f);
            acc = fmaf(a, dec_w2[j * kS + d], acc);
        }
        table[k * kS + d] = acc + dec_b2[d];
    }
    // weight packing: 3*128 rows of 64 floats + compact b1 slab
    if (t < 3 * kH) {
        const int p = t >> 7;
        const int j = t & (kH - 1);
        const float* w1 = (p == 0) ? q_w1 : (p == 1) ? gi_w1 : go_w1;
        const float* w2 = (p == 0) ? q_w2 : (p == 1) ? gi_w2 : go_w2;
        const float* b1 = (p == 0) ? q_b1 : (p == 1) ? gi_b1 : go_b1;
        float* row = pw + (size_t)(p * kH + j) * 64;
        for (int i = 0; i < kD; ++i) row[i] = w1[i * kH + j];
        for (int s = 0; s < kS; ++s) row[32 + s] = w2[j * kS + s];
        pb1[t] = b1[j];
    }
}

// -------- main ------------------------------------------------------------
// Fused quad-broadcast FMA: acc += (weight from quad-lane g) * h.
// DPP applies to src0 only; sources G* are ds_read-written (never VALU),
// so no VALU->DPP wait-state hazard. v_fmac_f32 is fused (fmaf-exact).
#define FMAC_BC0(acc, w, h) asm("v_fmac_f32_dpp %0, %1, %2 quad_perm:[0,0,0,0] row_mask:0xf bank_mask:0xf" : "+v"(acc) : "v"(w), "v"(h))
#define FMAC_BC1(acc, w, h) asm("v_fmac_f32_dpp %0, %1, %2 quad_perm:[1,1,1,1] row_mask:0xf bank_mask:0xf" : "+v"(acc) : "v"(w), "v"(h))
#define FMAC_BC2(acc, w, h) asm("v_fmac_f32_dpp %0, %1, %2 quad_perm:[2,2,2,2] row_mask:0xf bank_mask:0xf" : "+v"(acc) : "v"(w), "v"(h))
#define FMAC_BC3(acc, w, h) asm("v_fmac_f32_dpp %0, %1, %2 quad_perm:[3,3,3,3] row_mask:0xf bank_mask:0xf" : "+v"(acc) : "v"(w), "v"(h))

// 4 fmacs of one float4 block into acc (same chain order as R4's CHAIN8)
#define DOT4(acc, BCN, G, h0) \
    BCN(acc, G.x, hv[(h0) + 0]); BCN(acc, G.y, hv[(h0) + 1]); \
    BCN(acc, G.z, hv[(h0) + 2]); BCN(acc, G.w, hv[(h0) + 3]);

#define R14(s0, BCN, G) \
    BCN(lg[(s0) + 0], G.x, a); BCN(lg[(s0) + 1], G.y, a); \
    BCN(lg[(s0) + 2], G.z, a); BCN(lg[(s0) + 3], G.w, a);

__device__ __forceinline__ void stage_slab(const float* __restrict__ src,
                                           float* __restrict__ wl, int tid)
{
    __syncthreads();   // previous pass done reading LDS
    const float4* __restrict__ s4 = reinterpret_cast<const float4*>(src);
    float4* __restrict__ d4 = reinterpret_cast<float4*>(wl);
    #pragma unroll
    for (int k = 0; k < 8; ++k) d4[k * 256 + tid] = s4[k * 256 + tid];
    __syncthreads();
}

__device__ __forceinline__ void mlp_pass(const float* __restrict__ hv,
                                         const float* __restrict__ wls, // + 4*(tid&3)
                                         float b1lo, float b1hi,
                                         const float* __restrict__ b2,
                                         float* __restrict__ lg)
{
    #pragma unroll
    for (int s = 0; s < kS; ++s) lg[s] = 0.0f;
    #pragma unroll 1
    for (int j = 0; j < kH; ++j) {
        const float* __restrict__ row = wls + j * 64;
        // lane (tid&3)=g reads blocks {0,4,8,12}+g of 16 float4 blocks:
        // each ds_read_b128 hits 16 disjoint banks -> conflict-free broadcast.
        const float4 G0 = *reinterpret_cast<const float4*>(row +  0);
        const float4 G1 = *reinterpret_cast<const float4*>(row + 16);
        const float4 G2 = *reinterpret_cast<const float4*>(row + 32);
        const float4 G3 = *reinterpret_cast<const float4*>(row + 48);
        const float bsel = (j < 64) ? b1lo : b1hi;
        const float bias = __uint_as_float(
            (unsigned)__builtin_amdgcn_readlane((int)__float_as_uint(bsel), j & 63));
        // phase 1: w1 column dot, 4 independent chains (order == R1..R4)
        float a0 = 0.f, a1 = 0.f, a2 = 0.f, a3 = 0.f;
        DOT4(a0, FMAC_BC0, G0, 0)  DOT4(a0, FMAC_BC1, G0, 4)
        DOT4(a1, FMAC_BC2, G0, 8)  DOT4(a1, FMAC_BC3, G0, 12)
        DOT4(a2, FMAC_BC0, G1, 16) DOT4(a2, FMAC_BC1, G1, 20)
        DOT4(a3, FMAC_BC2, G1, 24) DOT4(a3, FMAC_BC3, G1, 28)
        float a = ((a0 + a1) + (a2 + a3)) + bias;  // dot, then bias (matches np)
        a = fmaxf(a, 0.0f);
        // phase 2: w2 row rank-1 update, s ascending (order == R1..R4)
        R14(0,  FMAC_BC0, G2) R14(4,  FMAC_BC1, G2)
        R14(8,  FMAC_BC2, G2) R14(12, FMAC_BC3, G2)
        R14(16, FMAC_BC0, G3) R14(20, FMAC_BC1, G3)
        R14(24, FMAC_BC2, G3) R14(28, FMAC_BC3, G3)
    }
    #pragma unroll
    for (int s = 0; s < kS; ++s) lg[s] += b2[s];
}

__device__ __forceinline__ float tree_sum32(const float* __restrict__ v)
{
    float b0 = 0.f, b1 = 0.f, b2 = 0.f, b3 = 0.f;
    #pragma unroll
    for (int i = 0; i < 8; ++i) {
        b0 += v[i]; b1 += v[i + 8]; b2 += v[i + 16]; b3 += v[i + 24];
    }
    return (b0 + b1) + (b2 + b3);   // pairwise-ish, like np.sum
}

__device__ __forceinline__ void softmax32(const float* __restrict__ lg,
                                          float* __restrict__ p)
{
    float m = lg[0];
    #pragma unroll
    for (int s = 1; s < kS; ++s) m = fmaxf(m, lg[s]);
    float e[kS];
    #pragma unroll
    for (int s = 0; s < kS; ++s) e[s] = expf(lg[s] - m);
    const float Z = tree_sum32(e);
    #pragma unroll
    for (int s = 0; s < kS; ++s) p[s] = e[s] / Z;  // precise div, like np
}

__global__ __launch_bounds__(256, 3) void main_kernel(
    const float* __restrict__ h, const float* __restrict__ u,
    const float* __restrict__ qb2, const float* __restrict__ gib2,
    const float* __restrict__ gob2,
    const float* __restrict__ pw, const float* __restrict__ pb1,
    const float* __restrict__ table, float* __restrict__ out)
{
    __shared__ float wl[kH * 64];   // 32768 B slab, restaged per pass
    const int tid = threadIdx.x;
    const int lane = tid & 63;
    const int b = blockIdx.x * 256 + tid;
    const float* __restrict__ wls = wl + ((tid & 3) << 2);

    float hv[kD];
    {
        const float4* h4 = reinterpret_cast<const float4*>(h + (size_t)b * kD);
        #pragma unroll
        for (int i = 0; i < 8; ++i) {
            float4 t = h4[i];
            hv[4 * i + 0] = t.x; hv[4 * i + 1] = t.y;
            hv[4 * i + 2] = t.z; hv[4 * i + 3] = t.w;
        }
    }

    float lg[kS], q[kS], gi[kS];

    stage_slab(pw, wl, tid);
    mlp_pass(hv, wls, pb1[lane], pb1[64 + lane], qb2, lg);
    softmax32(lg, q);

    stage_slab(pw + kH * 64, wl, tid);
    mlp_pass(hv, wls, pb1[128 + lane], pb1[192 + lane], gib2, lg);
    softmax32(lg, gi);

    stage_slab(pw + 2 * kH * 64, wl, tid);
    mlp_pass(hv, wls, pb1[256 + lane], pb1[320 + lane], gob2, lg);

    // g_out softmax fused with gumbel argmax (y never materialized)
    float m3 = lg[0];
    #pragma unroll
    for (int s = 1; s < kS; ++s) m3 = fmaxf(m3, lg[s]);
    float e3[kS];
    #pragma unroll
    for (int s = 0; s < kS; ++s) e3[s] = expf(lg[s] - m3);
    const float Z3 = tree_sum32(e3);
    const float qs = tree_sum32(q);   // == sum(q), computed like the reference

    float uv[kS];
    {
        const float4* u4 = reinterpret_cast<const float4*>(u + (size_t)b * kS);
        #pragma unroll
        for (int i = 0; i < 8; ++i) {
            float4 t = u4[i];
            uv[4 * i + 0] = t.x; uv[4 * i + 1] = t.y;
            uv[4 * i + 2] = t.z; uv[4 * i + 3] = t.w;
        }
    }

    float best = -__builtin_inff();
    int bi = 0;
    {
        #pragma clang fp contract(off)   // match np's per-op rounding here
        #pragma unroll
        for (int s = 0; s < kS; ++s) {
            const float gos = e3[s] / Z3;
            const float t1 = gi[s] * (qs - q[s]);
            const float t2 = gos * q[s];
            const float qn = q[s] + (t1 + t2);
            const float gn = -logf(-logf(uv[s] + 1e-20f) + 1e-20f);
            const float v  = logf(qn + 1e-12f) + gn;
            if (v > best) { best = v; bi = s; }   // strict >: first-index ties, like np.argmax
        }
    }

    // out[b,:] = table[bi,:]
    const float4* trow = reinterpret_cast<const float4*>(table + (size_t)bi * kS);
    float4* orow = reinterpret_cast<float4*>(out + (size_t)b * kD);
    #pragma unroll
    for (int i = 0; i < 8; ++i) orow[i] = trow[i];
}

extern "C" void kernel_launch(void* const* d_in, const int* in_sizes, int n_in,
                              void* d_out, int out_size, void* d_ws, size_t ws_size,
                              hipStream_t stream)
{
    const float* h      = (const float*)d_in[0];
    const float* u      = (const float*)d_in[1];
    const float* q_w1   = (const float*)d_in[2];
    const float* q_b1   = (const float*)d_in[3];
    const float* q_w2   = (const float*)d_in[4];
    const float* q_b2   = (const float*)d_in[5];
    const float* gi_w1  = (const float*)d_in[6];
    const float* gi_b1  = (const float*)d_in[7];
    const float* gi_w2  = (const float*)d_in[8];
    const float* gi_b2  = (const float*)d_in[9];
    const float* go_w1  = (const float*)d_in[10];
    const float* go_b1  = (const float*)d_in[11];
    const float* go_w2  = (const float*)d_in[12];
    const float* go_b2  = (const float*)d_in[13];
    const float* dec_w1 = (const float*)d_in[14];
    const float* dec_b1 = (const float*)d_in[15];
    const float* dec_w2 = (const float*)d_in[16];
    const float* dec_b2 = (const float*)d_in[17];

    float* pw    = (float*)d_ws;                       // 98304 B
    float* pb1   = (float*)((char*)d_ws + 98304);      //  1536 B
    float* table = (float*)((char*)d_ws + 99840);      //  4096 B
    float* out   = (float*)d_out;

    prep_kernel<<<1, 1024, 0, stream>>>(q_w1, q_b1, q_w2, gi_w1, gi_b1, gi_w2,
                                        go_w1, go_b1, go_w2,
                                        dec_w1, dec_b1, dec_w2, dec_b2,
                                        pw, pb1, table);
    main_kernel<<<kB / 256, 256, 0, stream>>>(h, u, q_b2, gi_b2, go_b2,
                                              pw, pb1, table, out);
}

// Round 6
// 617.157 us; speedup vs baseline: 4.3583x; 1.0623x over previous
//
#include <hip/hip_runtime.h>
#include <math.h>
#include <stdint.h>

// NeuralMJP forward, MI355X/gfx950.
//  * sample == one-hot(argmax(logits)) in fwd -> decoder = 32x32 table.
//  * argmax(softmax(z)) == argmax(z) -> y never materialized.
//  * fp32 only (no fp32 MFMA; bf16 flips Gumbel argmaxes -> catastrophic).
//  * Weight-delivery ladder (uniform data replicates on every pipe's return
//    path -> cost is per-instruction):
//      R1 all-SMEM: per-j lgkmcnt(0) drain vs K$/L2 latency -> 38%, 670us.
//      R2 LDS 16x uniform b128/j: DS-pipe-bound, 818us.
//      R4 VMEM: L1 returns 1KiB/wave-load, 1530us.
//      R5 LDS quad-split + DPP-fmac: 558us, but measured ~6cyc per
//         v_fmac_f32_dpp (387 cyc/j vs 140 ideal) - DPP issue cost and/or
//         8-deep dep chains in my macro order.
//      R6 (this): phase-1 w1 via SGPR operand of plain v_fmac (broadcast
//         free, 2cyc), unroll 2 to amortize the lgkmcnt drain; phase-2 w2
//         keeps quad-split DPP (independent accums, 2 ds_read_b128/j);
//         w2 slab (48KB, all 3 passes) staged into LDS once.

constexpr int kB = 524288;  // batch
constexpr int kD = 32;      // input dim
constexpr int kH = 128;     // hidden
constexpr int kS = 32;      // states

// d_ws layout (bytes):
//   pw1   @ 0     : 3*128*32 f32 = 49152   row j of pass p = w1_p[:,j]
//   pb1   @ 49152 : 3*128   f32 = 1536
//   table @ 50688 : 32*32   f32 = 4096

// -------- prep: pack w1 (transposed) + b1 + decoder table -----------------
__global__ __launch_bounds__(1024) void prep_kernel(
    const float* __restrict__ q_w1,  const float* __restrict__ q_b1,
    const float* __restrict__ gi_w1, const float* __restrict__ gi_b1,
    const float* __restrict__ go_w1, const float* __restrict__ go_b1,
    const float* __restrict__ dec_w1, const float* __restrict__ dec_b1,
    const float* __restrict__ dec_w2, const float* __restrict__ dec_b2,
    float* __restrict__ pw1, float* __restrict__ pb1, float* __restrict__ table)
{
    const int t = threadIdx.x;
    // decoder table: row k = relu(dec_w1[k,:] + dec_b1) @ dec_w2 + dec_b2
    {
        const int k = t >> 5, d = t & 31;
        float acc = 0.0f;
        #pragma unroll 4
        for (int j = 0; j < kH; ++j) {
            float a = dec_w1[k * kH + j] + dec_b1[j];
            a = fmaxf(a, 0.0f);
            acc = fmaf(a, dec_w2[j * kS + d], acc);
        }
        table[k * kS + d] = acc + dec_b2[d];
    }
    // w1 transposed pack: 3*128 rows of 32 floats + compact b1 slab
    if (t < 3 * kH) {
        const int p = t >> 7;
        const int j = t & (kH - 1);
        const float* w1 = (p == 0) ? q_w1 : (p == 1) ? gi_w1 : go_w1;
        const float* b1 = (p == 0) ? q_b1 : (p == 1) ? gi_b1 : go_b1;
        float* row = pw1 + (size_t)(p * kH + j) * 32;
        for (int i = 0; i < kD; ++i) row[i] = w1[i * kH + j];
        pb1[t] = b1[j];
    }
}

// -------- main ------------------------------------------------------------
// Fused quad-broadcast FMA: acc += (w2 element from quad-lane g) * a.
// DPP applies to src0 only; src0 is ds_read-written (never VALU) -> no
// VALU->DPP wait-state hazard. v_fmac_f32 is fused (fmaf-exact).
#define FMAC_BC0(acc, w, h) asm("v_fmac_f32_dpp %0, %1, %2 quad_perm:[0,0,0,0] row_mask:0xf bank_mask:0xf" : "+v"(acc) : "v"(w), "v"(h))
#define FMAC_BC1(acc, w, h) asm("v_fmac_f32_dpp %0, %1, %2 quad_perm:[1,1,1,1] row_mask:0xf bank_mask:0xf" : "+v"(acc) : "v"(w), "v"(h))
#define FMAC_BC2(acc, w, h) asm("v_fmac_f32_dpp %0, %1, %2 quad_perm:[2,2,2,2] row_mask:0xf bank_mask:0xf" : "+v"(acc) : "v"(w), "v"(h))
#define FMAC_BC3(acc, w, h) asm("v_fmac_f32_dpp %0, %1, %2 quad_perm:[3,3,3,3] row_mask:0xf bank_mask:0xf" : "+v"(acc) : "v"(w), "v"(h))

#define R14(s0, BCN, G) \
    BCN(lg[(s0) + 0], G.x, a); BCN(lg[(s0) + 1], G.y, a); \
    BCN(lg[(s0) + 2], G.z, a); BCN(lg[(s0) + 3], G.w, a);

__device__ __forceinline__ void mlp_pass(const float* __restrict__ hv,
                                         const float* __restrict__ w1b,  // uniform -> s_load
                                         const float* __restrict__ wq,   // LDS + 4*(tid&3)
                                         float b1lo, float b1hi,
                                         const float* __restrict__ b2,
                                         float* __restrict__ lg)
{
    #pragma unroll
    for (int s = 0; s < kS; ++s) lg[s] = 0.0f;
    #pragma unroll 2   // amortize the lgkmcnt drain for s_loads over 2 iters
    for (int j = 0; j < kH; ++j) {
        // phase-2 weights: quad-split LDS reads issued early (latency hides
        // under phase-1 fmacs). Each b128 hits 16 disjoint banks.
        const float4 W0 = *reinterpret_cast<const float4*>(wq + j * kS);
        const float4 W1 = *reinterpret_cast<const float4*>(wq + j * kS + 16);
        // phase-1 weights: wave-uniform pointer -> s_load, scalar fmac srcs
        const float* __restrict__ w1r = w1b + j * kD;
        const float bsel = (j < 64) ? b1lo : b1hi;
        const float bias = __uint_as_float(
            (unsigned)__builtin_amdgcn_readlane((int)__float_as_uint(bsel), j & 63));
        // phase 1: 4 chains round-robin interleaved (per-chain order == R1..R5)
        float a0 = 0.f, a1 = 0.f, a2 = 0.f, a3 = 0.f;
        #pragma unroll
        for (int i = 0; i < 8; ++i) {
            a0 = fmaf(hv[i],      w1r[i],      a0);
            a1 = fmaf(hv[i + 8],  w1r[i + 8],  a1);
            a2 = fmaf(hv[i + 16], w1r[i + 16], a2);
            a3 = fmaf(hv[i + 24], w1r[i + 24], a3);
        }
        float a = ((a0 + a1) + (a2 + a3)) + bias;  // dot, then bias (matches np)
        a = fmaxf(a, 0.0f);
        // phase 2: rank-1 update, s ascending (order == R1..R5), indep accums
        R14(0,  FMAC_BC0, W0) R14(4,  FMAC_BC1, W0)
        R14(8,  FMAC_BC2, W0) R14(12, FMAC_BC3, W0)
        R14(16, FMAC_BC0, W1) R14(20, FMAC_BC1, W1)
        R14(24, FMAC_BC2, W1) R14(28, FMAC_BC3, W1)
    }
    #pragma unroll
    for (int s = 0; s < kS; ++s) lg[s] += b2[s];
}

__device__ __forceinline__ float tree_sum32(const float* __restrict__ v)
{
    float b0 = 0.f, b1 = 0.f, b2 = 0.f, b3 = 0.f;
    #pragma unroll
    for (int i = 0; i < 8; ++i) {
        b0 += v[i]; b1 += v[i + 8]; b2 += v[i + 16]; b3 += v[i + 24];
    }
    return (b0 + b1) + (b2 + b3);   // pairwise-ish, like np.sum
}

__device__ __forceinline__ void softmax32(const float* __restrict__ lg,
                                          float* __restrict__ p)
{
    float m = lg[0];
    #pragma unroll
    for (int s = 1; s < kS; ++s) m = fmaxf(m, lg[s]);
    float e[kS];
    #pragma unroll
    for (int s = 0; s < kS; ++s) e[s] = expf(lg[s] - m);
    const float Z = tree_sum32(e);
    #pragma unroll
    for (int s = 0; s < kS; ++s) p[s] = e[s] / Z;  // precise div, like np
}

__global__ __launch_bounds__(256, 3) void main_kernel(
    const float* __restrict__ h, const float* __restrict__ u,
    const float* __restrict__ qb2, const float* __restrict__ gib2,
    const float* __restrict__ gob2,
    const float* __restrict__ q_w2, const float* __restrict__ gi_w2,
    const float* __restrict__ go_w2,
    const float* __restrict__ pw1, const float* __restrict__ pb1,
    const float* __restrict__ table, float* __restrict__ out)
{
    __shared__ float wl[3 * kH * kS];   // 48KB: all 3 passes' w2, staged once
    const int tid = threadIdx.x;
    const int lane = tid & 63;
    const int b = blockIdx.x * 256 + tid;

    // stage w2 slabs (each 1024 float4, 4 per thread per slab)
    {
        float4* __restrict__ d4 = reinterpret_cast<float4*>(wl);
        const float4* __restrict__ s0 = reinterpret_cast<const float4*>(q_w2);
        const float4* __restrict__ s1 = reinterpret_cast<const float4*>(gi_w2);
        const float4* __restrict__ s2 = reinterpret_cast<const float4*>(go_w2);
        #pragma unroll
        for (int k = 0; k < 4; ++k) {
            d4[k * 256 + tid]        = s0[k * 256 + tid];
            d4[1024 + k * 256 + tid] = s1[k * 256 + tid];
            d4[2048 + k * 256 + tid] = s2[k * 256 + tid];
        }
    }

    float hv[kD];
    {
        const float4* h4 = reinterpret_cast<const float4*>(h + (size_t)b * kD);
        #pragma unroll
        for (int i = 0; i < 8; ++i) {
            float4 t = h4[i];
            hv[4 * i + 0] = t.x; hv[4 * i + 1] = t.y;
            hv[4 * i + 2] = t.z; hv[4 * i + 3] = t.w;
        }
    }
    __syncthreads();

    const float* __restrict__ wq = wl + ((tid & 3) << 2);
    float lg[kS], q[kS], gi[kS];

    mlp_pass(hv, pw1,              wq,              pb1[lane], pb1[64 + lane],  qb2,  lg);
    softmax32(lg, q);
    mlp_pass(hv, pw1 + kH * kD,    wq + kH * kS,    pb1[128 + lane], pb1[192 + lane], gib2, lg);
    softmax32(lg, gi);
    mlp_pass(hv, pw1 + 2 * kH * kD, wq + 2 * kH * kS, pb1[256 + lane], pb1[320 + lane], gob2, lg);

    // g_out softmax fused with gumbel argmax (y never materialized)
    float m3 = lg[0];
    #pragma unroll
    for (int s = 1; s < kS; ++s) m3 = fmaxf(m3, lg[s]);
    float e3[kS];
    #pragma unroll
    for (int s = 0; s < kS; ++s) e3[s] = expf(lg[s] - m3);
    const float Z3 = tree_sum32(e3);
    const float qs = tree_sum32(q);   // == sum(q), computed like the reference

    float uv[kS];
    {
        const float4* u4 = reinterpret_cast<const float4*>(u + (size_t)b * kS);
        #pragma unroll
        for (int i = 0; i < 8; ++i) {
            float4 t = u4[i];
            uv[4 * i + 0] = t.x; uv[4 * i + 1] = t.y;
            uv[4 * i + 2] = t.z; uv[4 * i + 3] = t.w;
        }
    }

    float best = -__builtin_inff();
    int bi = 0;
    {
        #pragma clang fp contract(off)   // match np's per-op rounding here
        #pragma unroll
        for (int s = 0; s < kS; ++s) {
            const float gos = e3[s] / Z3;
            const float t1 = gi[s] * (qs - q[s]);
            const float t2 = gos * q[s];
            const float qn = q[s] + (t1 + t2);
            const float gn = -logf(-logf(uv[s] + 1e-20f) + 1e-20f);
            const float v  = logf(qn + 1e-12f) + gn;
            if (v > best) { best = v; bi = s; }   // strict >: first-index ties, like np.argmax
        }
    }

    // out[b,:] = table[bi,:]
    const float4* trow = reinterpret_cast<const float4*>(table + (size_t)bi * kS);
    float4* orow = reinterpret_cast<float4*>(out + (size_t)b * kD);
    #pragma unroll
    for (int i = 0; i < 8; ++i) orow[i] = trow[i];
}

extern "C" void kernel_launch(void* const* d_in, const int* in_sizes, int n_in,
                              void* d_out, int out_size, void* d_ws, size_t ws_size,
                              hipStream_t stream)
{
    const float* h      = (const float*)d_in[0];
    const float* u      = (const float*)d_in[1];
    const float* q_w1   = (const float*)d_in[2];
    const float* q_b1   = (const float*)d_in[3];
    const float* q_w2   = (const float*)d_in[4];
    const float* q_b2   = (const float*)d_in[5];
    const float* gi_w1  = (const float*)d_in[6];
    const float* gi_b1  = (const float*)d_in[7];
    const float* gi_w2  = (const float*)d_in[8];
    const float* gi_b2  = (const float*)d_in[9];
    const float* go_w1  = (const float*)d_in[10];
    const float* go_b1  = (const float*)d_in[11];
    const float* go_w2  = (const float*)d_in[12];
    const float* go_b2  = (const float*)d_in[13];
    const float* dec_w1 = (const float*)d_in[14];
    const float* dec_b1 = (const float*)d_in[15];
    const float* dec_w2 = (const float*)d_in[16];
    const float* dec_b2 = (const float*)d_in[17];

    float* pw1   = (float*)d_ws;                       // 49152 B
    float* pb1   = (float*)((char*)d_ws + 49152);      //  1536 B
    float* table = (float*)((char*)d_ws + 50688);      //  4096 B
    float* out   = (float*)d_out;

    prep_kernel<<<1, 1024, 0, stream>>>(q_w1, q_b1, gi_w1, gi_b1, go_w1, go_b1,
                                        dec_w1, dec_b1, dec_w2, dec_b2,
                                        pw1, pb1, table);
    main_kernel<<<kB / 256, 256, 0, stream>>>(h, u, q_b2, gi_b2, go_b2,
                                              q_w2, gi_w2, go_w2,
                                              pw1, pb1, table, out);
}